// Round 1
// baseline (198.474 us; speedup 1.0000x reference)
//
#include <hip/hip_runtime.h>

// Problem constants (from reference): B=16384 bags, HIST=50, K=128, EMB_DIM=3,
// MLP: (12,K)+(12,) -> (6,12)+(6,) -> (3,6)+(3,), no activation -> collapsible.

#define KDIM 128

// --- Kernel 1: collapse the 3 linear layers into Wc[3][128], bc[3] ----------
// Wc[o][k] = sum_i w2[o][i] * sum_j w1[i][j] * w0[j][k]
// bc[o]    = sum_i w2[o][i] * (sum_j w1[i][j]*b0[j] + b1[i]) + b2[o]
__global__ __launch_bounds__(KDIM) void collapse_weights_kernel(
    const float* __restrict__ w0, const float* __restrict__ b0,
    const float* __restrict__ w1, const float* __restrict__ b1,
    const float* __restrict__ w2, const float* __restrict__ b2,
    float* __restrict__ ws) // ws[0..383] = Wc, ws[384..386] = bc
{
    __shared__ float t[6][KDIM];   // w1 @ w0  (6 x 128)
    __shared__ float tb[6];        // w1 @ b0 + b1

    const int k = threadIdx.x;     // 0..127
    for (int i = 0; i < 6; ++i) {
        float acc = 0.f;
        for (int j = 0; j < 12; ++j)
            acc += w1[i * 12 + j] * w0[j * KDIM + k];
        t[i][k] = acc;
    }
    if (k < 6) {
        float acc = 0.f;
        for (int j = 0; j < 12; ++j)
            acc += w1[k * 12 + j] * b0[j];
        tb[k] = acc + b1[k];
    }
    __syncthreads();

    for (int o = 0; o < 3; ++o) {
        float acc = 0.f;
        for (int i = 0; i < 6; ++i)
            acc += w2[o * 6 + i] * t[i][k];
        ws[o * KDIM + k] = acc;
    }
    if (k == 0) {
        for (int o = 0; o < 3; ++o) {
            float acc = 0.f;
            for (int i = 0; i < 6; ++i)
                acc += w2[o * 6 + i] * tb[i];
            ws[3 * KDIM + o] = acc + b2[o];
        }
    }
}

// --- Kernel 2: fused embedding-bag mean + collapsed MLP ---------------------
// One 64-lane wave per bag. Lanes 0..count-1 gather embedding rows (max MLP
// of memory-level parallelism for the latency-bound gather); all lanes help
// with the 128-wide MLP dot (2 elems/lane, coalesced float2). Butterfly
// shfl_xor reduction leaves results in every lane; lanes 0..11 write the 12
// output columns coalesced.
__global__ __launch_bounds__(256) void fused_embbag_mlp_kernel(
    const int* __restrict__ eb_input,     // [N] indices (int32)
    const int* __restrict__ eb_offset,    // [B] bag starts
    const float* __restrict__ mlp_input,  // [B, 128]
    const float* __restrict__ emb_weight, // [NUM_EMB, 3]
    const float* __restrict__ ws,         // Wc[3][128], bc[3]
    float* __restrict__ out,              // [B, 12]
    int n_indices, int num_bags)
{
    const int lane = threadIdx.x & 63;
    const int wave = threadIdx.x >> 6;
    const int bag  = blockIdx.x * (blockDim.x >> 6) + wave;
    if (bag >= num_bags) return;

    const int start = eb_offset[bag];
    const int end   = (bag + 1 < num_bags) ? eb_offset[bag + 1] : n_indices;

    // Embedding gather partials (each lane: at most 1 row for HIST=50)
    float s0 = 0.f, s1 = 0.f, s2 = 0.f;
    for (int i = start + lane; i < end; i += 64) {
        const int idx = eb_input[i];
        const float* r = emb_weight + (long long)idx * 3;
        s0 += r[0];
        s1 += r[1];
        s2 += r[2];
    }

    // MLP partials: lane handles x[2*lane], x[2*lane+1]
    const float* x = mlp_input + (long long)bag * KDIM;
    const float2 xv = *(const float2*)(x + 2 * lane);
    const int c = 2 * lane;
    float m0 = xv.x * ws[0 * KDIM + c] + xv.y * ws[0 * KDIM + c + 1];
    float m1 = xv.x * ws[1 * KDIM + c] + xv.y * ws[1 * KDIM + c + 1];
    float m2 = xv.x * ws[2 * KDIM + c] + xv.y * ws[2 * KDIM + c + 1];

    // Butterfly reduction across the 64-lane wave (all lanes end with totals)
    #pragma unroll
    for (int off = 32; off > 0; off >>= 1) {
        s0 += __shfl_xor(s0, off, 64);
        s1 += __shfl_xor(s1, off, 64);
        s2 += __shfl_xor(s2, off, 64);
        m0 += __shfl_xor(m0, off, 64);
        m1 += __shfl_xor(m1, off, 64);
        m2 += __shfl_xor(m2, off, 64);
    }

    const float cnt = (float)(end - start);
    const float inv = 1.0f / fmaxf(cnt, 1.0f);
    const float e0 = s0 * inv, e1 = s1 * inv, e2 = s2 * inv;
    const float o9  = m0 + ws[3 * KDIM + 0];
    const float o10 = m1 + ws[3 * KDIM + 1];
    const float o11 = m2 + ws[3 * KDIM + 2];

    if (lane < 12) {
        float v;
        if (lane < 9) {
            const int r3 = lane - (lane >= 3 ? (lane >= 6 ? 6 : 3) : 0); // lane % 3
            v = (r3 == 0) ? e0 : (r3 == 1 ? e1 : e2);
        } else {
            v = (lane == 9) ? o9 : (lane == 10 ? o10 : o11);
        }
        out[(long long)bag * 12 + lane] = v;
    }
}

extern "C" void kernel_launch(void* const* d_in, const int* in_sizes, int n_in,
                              void* d_out, int out_size, void* d_ws, size_t ws_size,
                              hipStream_t stream) {
    const int*   eb_input   = (const int*)d_in[0];   // [B*HIST] int32
    const int*   eb_offset  = (const int*)d_in[1];   // [B] int32
    const float* mlp_input  = (const float*)d_in[2]; // [B,128]
    const float* emb_weight = (const float*)d_in[3]; // [10M,3]
    const float* w0 = (const float*)d_in[4];
    const float* b0 = (const float*)d_in[5];
    const float* w1 = (const float*)d_in[6];
    const float* b1 = (const float*)d_in[7];
    const float* w2 = (const float*)d_in[8];
    const float* b2 = (const float*)d_in[9];
    float* out = (float*)d_out;
    float* ws  = (float*)d_ws;   // 387 floats used

    const int n_indices = in_sizes[0];
    const int num_bags  = in_sizes[1];

    collapse_weights_kernel<<<1, KDIM, 0, stream>>>(w0, b0, w1, b1, w2, b2, ws);

    const int waves_per_block = 4;                 // 256 threads
    const int grid = (num_bags + waves_per_block - 1) / waves_per_block;
    fused_embbag_mlp_kernel<<<grid, 256, 0, stream>>>(
        eb_input, eb_offset, mlp_input, emb_weight, ws, out, n_indices, num_bags);
}